// Round 4
// baseline (223.485 us; speedup 1.0000x reference)
//
#include <hip/hip_runtime.h>

// ---- types ----
typedef __bf16        bf16x8 __attribute__((ext_vector_type(8)));
typedef float         f32x4  __attribute__((ext_vector_type(4)));
typedef unsigned short u16x4 __attribute__((ext_vector_type(4)));
typedef unsigned short u16x8 __attribute__((ext_vector_type(8)));
typedef unsigned int  u32x4  __attribute__((ext_vector_type(4)));

#define MFMA16(a,b,c) __builtin_amdgcn_mfma_f32_16x16x32_bf16((a),(b),(c),0,0,0)

static __device__ __forceinline__ unsigned short f2bf(float f) {
  unsigned int u = __builtin_bit_cast(unsigned int, f);
  u += 0x7fffu + ((u >> 16) & 1u);          // RNE; inputs are finite
  return (unsigned short)(u >> 16);
}
// pack 2 floats -> bf16x2 dword, round-half-up via +0x8000 then byte-perm
static __device__ __forceinline__ unsigned int pk2(float a, float b) {
  unsigned int ua = __builtin_bit_cast(unsigned int, a) + 0x8000u;
  unsigned int ub = __builtin_bit_cast(unsigned int, b) + 0x8000u;
  return __builtin_amdgcn_perm(ub, ua, 0x07060302u);
}
static __device__ __forceinline__ unsigned int pk2rne(float a, float b) {
  return (unsigned int)f2bf(a) | ((unsigned int)f2bf(b) << 16);
}
static __device__ __forceinline__ bf16x8 as_bf(u32x4 v) {
  return __builtin_bit_cast(bf16x8, v);
}
static __device__ __forceinline__ float bf2f(unsigned short u) {
  return __builtin_bit_cast(float, ((unsigned int)u) << 16);
}
// async 16B-per-lane global->LDS DMA; LDS image = base + lane*16
static __device__ __forceinline__ void dma16(const unsigned short* g, unsigned short* l) {
  __builtin_amdgcn_global_load_lds((const __attribute__((address_space(1))) unsigned int*)g,
                                   (__attribute__((address_space(3))) unsigned int*)l, 16, 0, 0);
}

// Problem constants
#define SDIM 4096
#define CDIM 256
#define NHEAD 4
#define HDIM 64
#define NBATCH 2

// ---------------------------------------------------------------------------
// 1) merged prep: blocks 0..255 = GN partial stats, 256..319 = weight cast
__global__ __launch_bounds__(256) void k_prep(const float* __restrict__ x,
                                              const float* __restrict__ wq,
                                              const float* __restrict__ wo,
                                              unsigned short* __restrict__ wqb,
                                              unsigned short* __restrict__ wob,
                                              float2* __restrict__ Sp) {
  int j = blockIdx.x, i = threadIdx.x;
  if (j < 256) {
    const float* p = x + (size_t)(j >> 3) * 65536 + (size_t)(j & 7) * 8192;
    float s = 0.f, sq = 0.f;
#pragma unroll
    for (int r = 0; r < 8; ++r) {
      float4 v = *(const float4*)(p + (r * 256 + i) * 4);
      s  += v.x + v.y + v.z + v.w;
      sq += v.x * v.x + v.y * v.y + v.z * v.z + v.w * v.w;
    }
    __shared__ float rs[256], rq[256];
    rs[i] = s; rq[i] = sq;
    __syncthreads();
    for (int off = 128; off > 0; off >>= 1) {
      if (i < off) { rs[i] += rs[i + off]; rq[i] += rq[i + off]; }
      __syncthreads();
    }
    if (i == 0) Sp[j] = make_float2(rs[0], rq[0]);
  } else {
    int t = (j - 256) * 256 + i;
    int e = t * 16;
#pragma unroll
    for (int c = 0; c < 4; ++c) {
      int idx = e + c * 4;
      const float* src = (idx < 768 * 256) ? (wq + idx) : (wo + idx - 768 * 256);
      unsigned short* dst = (idx < 768 * 256) ? (wqb + idx) : (wob + idx - 768 * 256);
      float4 v = *(const float4*)src;
      u16x4 r; r[0] = f2bf(v.x); r[1] = f2bf(v.y); r[2] = f2bf(v.z); r[3] = f2bf(v.w);
      *(u16x4*)dst = r;
    }
  }
}

// ---------------------------------------------------------------------------
// 2) GN apply + transpose: x[b][c][s] fp32 -> xn[b][s][c] bf16 (stats from Sp)
__global__ __launch_bounds__(256) void k_gn_apply(const float* __restrict__ x,
                                                  const float2* __restrict__ Sp,
                                                  const float* __restrict__ gnw,
                                                  const float* __restrict__ gnb,
                                                  unsigned short* __restrict__ xn) {
  __shared__ __attribute__((aligned(16))) unsigned short sT[64 * 268];
  __shared__ float2 sStat[16];
  int b = blockIdx.y, s0 = blockIdx.x * 64;
  int i = threadIdx.x, lane = i & 63, w = i >> 6;
  if (i < 16) {
    float s = 0.f, sq = 0.f;
#pragma unroll
    for (int u = 0; u < 8; ++u) {
      float2 v = Sp[(b * 16 + i) * 8 + u];
      s += v.x; sq += v.y;
    }
    float mean = s * (1.f / 65536.f);
    float var  = sq * (1.f / 65536.f) - mean * mean;
    sStat[i] = make_float2(mean, rsqrtf(var + 1e-5f));
  }
  __syncthreads();
#pragma unroll 4
  for (int r = 0; r < 64; ++r) {
    int c = r * 4 + w;
    float v = x[((size_t)(b * CDIM + c)) * SDIM + s0 + lane];
    float2 st = sStat[c >> 4];
    float nv = (v - st.x) * st.y * gnw[c] + gnb[c];
    sT[lane * 268 + c] = f2bf(nv);
  }
  __syncthreads();
#pragma unroll
  for (int r = 0; r < 16; ++r) {
    int sl = r * 4 + w;
    u16x4 v = *(const u16x4*)&sT[sl * 268 + lane * 4];
    *(u16x4*)&xn[((size_t)(b * SDIM + s0 + sl)) * CDIM + lane * 4] = v;
  }
}

// ---------------------------------------------------------------------------
// 3/5) GEMM: D[o][s] = sum_c W[o][c] * X[b][s][c]  (K=256)
//  MODE 0 (QKV): epilogue repacks into MFMA frag-linear layouts:
//    Qf/Kf[bh][tile16 = s/16][ks = d/32][lane][8]  (Q pre-scaled by log2(e)/16)
//    Vf[bh][kt32 = s/32][dt = d/16][lane][8]
//  MODE 1 (proj): fp32 + bias + residual -> outf[b][o][s]
template <int M, int MODE>
__global__ __launch_bounds__(256) void k_gemm(const unsigned short* __restrict__ W,
                                              const unsigned short* __restrict__ X,
                                              unsigned short* __restrict__ Qf,
                                              unsigned short* __restrict__ Kf,
                                              unsigned short* __restrict__ Vf,
                                              float* __restrict__ outf,
                                              const float* __restrict__ bias,
                                              const float* __restrict__ resid) {
  __shared__ __attribute__((aligned(16))) unsigned short sX[64 * 40];
  __shared__ __attribute__((aligned(16))) unsigned short sB[64 * 68];  // bounce [s][o]
  int b = blockIdx.z, s0 = blockIdx.y * 64, o0 = blockIdx.x * 64;
  int i = threadIdx.x, lane = i & 63, w = i >> 6;
  int quad = lane >> 4, m = lane & 15;
  const unsigned short* Xb = X + ((size_t)b * SDIM + s0) * CDIM;
  int ss = i >> 2, cq = i & 3;

  f32x4 acc[4] = {};
#pragma unroll
  for (int k0 = 0; k0 < 256; k0 += 32) {
    u32x4 xv = *(const u32x4*)(Xb + ss * CDIM + k0 + cq * 8);
    *(u32x4*)&sX[ss * 40 + cq * 8] = xv;
    __syncthreads();
    bf16x8 a = as_bf(*(const u32x4*)(W + (o0 + w * 16 + m) * 256 + k0 + quad * 8));
#pragma unroll
    for (int st = 0; st < 4; ++st) {
      bf16x8 bx = as_bf(*(const u32x4*)&sX[(st * 16 + m) * 40 + quad * 8]);
      acc[st] = MFMA16(a, bx, acc[st]);
    }
    __syncthreads();
  }
  if (MODE == 1) {
#pragma unroll
    for (int st = 0; st < 4; ++st)
#pragma unroll
      for (int r = 0; r < 4; ++r) {
        int o = o0 + w * 16 + quad * 4 + r;
        int s = s0 + st * 16 + m;
        size_t idx = ((size_t)b * M + o) * SDIM + s;
        outf[idx] = acc[st][r] + bias[o] + resid[idx];
      }
  } else {
    int sec = (o0 >> 6) % 3;             // 0=Q, 1=K, 2=V
    int h   = o0 / 192;
    int bh  = b * NHEAD + h;
    float qs = (sec == 0) ? 0.09016844f : 1.0f;   // log2(e)/16 folded into Q
#pragma unroll
    for (int st = 0; st < 4; ++st) {
      uint2 pk = make_uint2(pk2rne(acc[st][0] * qs, acc[st][1] * qs),
                            pk2rne(acc[st][2] * qs, acc[st][3] * qs));
      *(uint2*)&sB[(st * 16 + m) * 68 + w * 16 + quad * 4] = pk;
    }
    __syncthreads();
    int lp = i & 63, qp = lp >> 4, mp = lp & 15, t = i >> 6;
    if (sec < 2) {
      unsigned short* base = (sec == 0) ? Qf : Kf;
#pragma unroll
      for (int ks = 0; ks < 2; ++ks) {
        const unsigned short* src = &sB[(t * 16 + mp) * 68 + ks * 32 + qp * 8];
        u16x4 lo = *(const u16x4*)src;
        u16x4 hi = *(const u16x4*)(src + 4);
        unsigned short* dst = base + ((((size_t)bh * 256 + (s0 >> 4) + t) * 2 + ks) * 64 + lp) * 8;
        *(u16x4*)dst = lo;
        *(u16x4*)(dst + 4) = hi;
      }
    } else {
      int kt32l = t >> 1, dts = (t & 1) * 2;
#pragma unroll
      for (int dd = 0; dd < 2; ++dd) {
        int dt = dts + dd;
        u16x8 v;
#pragma unroll
        for (int jj = 0; jj < 8; ++jj)
          v[jj] = sB[(kt32l * 32 + qp * 8 + jj) * 68 + dt * 16 + mp];
        unsigned short* dst = Vf + ((((size_t)bh * 128 + (s0 >> 5) + kt32l) * 4 + dt) * 64 + lp) * 8;
        *(u16x8*)dst = v;
      }
    }
  }
}

// ---------------------------------------------------------------------------
// 4) Flash attention, frag-linear inputs, shared LDS tiles, key-split blocks.
//    Block = (256-q tile, bh, ksplit), 4 waves share staged 32-key K/V tiles
//    (double-buffered global_load_lds, 1 barrier/iter). Fixed-max softmax.
//    Partials: Opb bf16 [ks][bh][q][64], Lp fp32 [ks][bh][q].
//    KS=8 -> grid 1024 blocks = 4 blocks/CU (16 waves/CU); lb(256,4).
template <int KS>
__global__ __launch_bounds__(256, 4) void k_attn(const unsigned short* __restrict__ Qf,
                                                 const unsigned short* __restrict__ Kf,
                                                 const unsigned short* __restrict__ Vf,
                                                 unsigned short* __restrict__ Opb,
                                                 float* __restrict__ Lp) {
  __shared__ __attribute__((aligned(16))) unsigned short sK[2][2048];
  __shared__ __attribute__((aligned(16))) unsigned short sV[2][2048];
  __shared__ __attribute__((aligned(16))) unsigned short sP[4][64 * 40];
  int bh = blockIdx.y, kk = blockIdx.z;
  int i = threadIdx.x, lane = i & 63, w = i >> 6;
  int quad = lane >> 4, m = lane & 15;
  int qbase = blockIdx.x * 256 + w * 64;
  constexpr int ITERS = SDIM / KS / 32;

  bf16x8 bq[4][2];
#pragma unroll
  for (int qt = 0; qt < 4; ++qt)
#pragma unroll
    for (int ks = 0; ks < 2; ++ks)
      bq[qt][ks] = as_bf(*(const u32x4*)(Qf +
        ((((size_t)bh * 256 + ((qbase >> 4) + qt)) * 2 + ks) * 64 + lane) * 8));

  f32x4 oacc[4][4] = {};
  float li[4] = {0.f, 0.f, 0.f, 0.f};

  auto dma = [&](int it, int buf) {
    int kb16 = kk * (ITERS * 2) + it * 2 + (w >> 1);
    dma16(Kf + ((((size_t)bh * 256 + kb16) * 2 + (w & 1)) * 64 + lane) * 8,
          &sK[buf][w * 512]);
    int kb32 = kk * ITERS + it;
    dma16(Vf + ((((size_t)bh * 128 + kb32) * 4 + w) * 64 + lane) * 8,
          &sV[buf][w * 512]);
  };
  dma(0, 0);

  for (int it = 0; it < ITERS; ++it) {
    int buf = it & 1;
    __syncthreads();
    if (it < ITERS - 1) dma(it + 1, buf ^ 1);

    bf16x8 ak[2][2], av[4];
#pragma unroll
    for (int ky = 0; ky < 2; ++ky)
#pragma unroll
      for (int ks = 0; ks < 2; ++ks)
        ak[ky][ks] = *(const bf16x8*)&sK[buf][((ky * 2 + ks) * 64 + lane) * 8];
#pragma unroll
    for (int dt = 0; dt < 4; ++dt)
      av[dt] = *(const bf16x8*)&sV[buf][(dt * 64 + lane) * 8];

#pragma unroll
    for (int qt = 0; qt < 4; ++qt) {
      f32x4 sc0 = {-18.f, -18.f, -18.f, -18.f};
      f32x4 sc1 = sc0;
      sc0 = MFMA16(ak[0][0], bq[qt][0], sc0);
      sc0 = MFMA16(ak[0][1], bq[qt][1], sc0);
      sc1 = MFMA16(ak[1][0], bq[qt][0], sc1);
      sc1 = MFMA16(ak[1][1], bq[qt][1], sc1);
      float p[8];
#pragma unroll
      for (int r = 0; r < 4; ++r) {
        p[r]     = __builtin_amdgcn_exp2f(sc0[r]);
        p[4 + r] = __builtin_amdgcn_exp2f(sc1[r]);
      }
      li[qt] += ((p[0] + p[1]) + (p[2] + p[3])) + ((p[4] + p[5]) + (p[6] + p[7]));
      int row = (qt * 16 + m) * 40;
      *(uint2*)&sP[w][row + quad * 4]      = make_uint2(pk2(p[0], p[1]), pk2(p[2], p[3]));
      *(uint2*)&sP[w][row + 16 + quad * 4] = make_uint2(pk2(p[4], p[5]), pk2(p[6], p[7]));
    }
#pragma unroll
    for (int qt = 0; qt < 4; ++qt) {
      bf16x8 bp = *(const bf16x8*)&sP[w][(qt * 16 + m) * 40 + quad * 8];
#pragma unroll
      for (int dt = 0; dt < 4; ++dt)
        oacc[qt][dt] = MFMA16(av[dt], bp, oacc[qt][dt]);
    }
  }

  size_t qg = (size_t)(kk * 8 + bh) * SDIM + qbase;
#pragma unroll
  for (int qt = 0; qt < 4; ++qt) {
    li[qt] += __shfl_xor(li[qt], 16);
    li[qt] += __shfl_xor(li[qt], 32);
  }
  if (quad == 0) {
#pragma unroll
    for (int qt = 0; qt < 4; ++qt) Lp[qg + qt * 16 + m] = li[qt];
  }
#pragma unroll
  for (int qt = 0; qt < 4; ++qt)
#pragma unroll
    for (int dt = 0; dt < 4; ++dt) {
      uint2 pk = make_uint2(pk2rne(oacc[qt][dt][0], oacc[qt][dt][1]),
                            pk2rne(oacc[qt][dt][2], oacc[qt][dt][3]));
      *(uint2*)&Opb[(qg + qt * 16 + m) * 64 + dt * 16 + quad * 4] = pk;
    }
}

// ---------------------------------------------------------------------------
// 5) combine partials: ao[b][q][h*64+d] = sum_ks Opb / sum_ks Lp  (bf16)
template <int KS>
__global__ __launch_bounds__(256) void k_combine(const unsigned short* __restrict__ Opb,
                                                 const float* __restrict__ Lp,
                                                 unsigned short* __restrict__ ao) {
  int gid = blockIdx.x * 256 + threadIdx.x;
  int bh = gid >> 14, rem = gid & 16383, q = rem >> 2, dq = rem & 3;
  float li = 0.f, o[16];
#pragma unroll
  for (int e = 0; e < 16; ++e) o[e] = 0.f;
#pragma unroll
  for (int ks = 0; ks < KS; ++ks) {
    size_t base = (size_t)(ks * 8 + bh) * SDIM + q;
    li += Lp[base];
    const unsigned short* p = Opb + base * 64 + dq * 16;
    u16x8 a = *(const u16x8*)p, b2 = *(const u16x8*)(p + 8);
#pragma unroll
    for (int e = 0; e < 8; ++e) { o[e] += bf2f(a[e]); o[8 + e] += bf2f(b2[e]); }
  }
  float inv = 1.f / li;
  unsigned int dw[8];
#pragma unroll
  for (int e = 0; e < 8; ++e) dw[e] = pk2rne(o[2 * e] * inv, o[2 * e + 1] * inv);
  unsigned short* dst = ao + ((size_t)((bh >> 2) * SDIM + q)) * CDIM + (bh & 3) * HDIM + dq * 16;
  *(u32x4*)dst       = u32x4{dw[0], dw[1], dw[2], dw[3]};
  *(u32x4*)(dst + 8) = u32x4{dw[4], dw[5], dw[6], dw[7]};
}

// ---------------------------------------------------------------------------
extern "C" void kernel_launch(void* const* d_in, const int* in_sizes, int n_in,
                              void* d_out, int out_size, void* d_ws, size_t ws_size,
                              hipStream_t stream) {
  const float* input = (const float*)d_in[0];
  const float* gnw   = (const float*)d_in[1];
  const float* gnb   = (const float*)d_in[2];
  const float* wq    = (const float*)d_in[3];
  const float* wo    = (const float*)d_in[4];
  const float* ob    = (const float*)d_in[5];
  float* out = (float*)d_out;

  char* ws = (char*)d_ws;
  unsigned short* xn  = (unsigned short*)(ws);                        // 4 MB [b][s][c]
  unsigned short* Qf  = (unsigned short*)(ws + (4ull  << 20));        // 4 MB frag-linear
  unsigned short* Kf  = (unsigned short*)(ws + (8ull  << 20));        // 4 MB
  unsigned short* Vf  = (unsigned short*)(ws + (12ull << 20));        // 4 MB
  unsigned short* ao  = (unsigned short*)(ws + (16ull << 20));        // 4 MB [b][s][c]
  unsigned short* wqb = (unsigned short*)(ws + (20ull << 20));        // 384 KB
  unsigned short* wob = (unsigned short*)(ws + (20ull << 20) + (1u << 19)); // 128 KB
  float2* Sp          = (float2*)(ws + (20ull << 20) + (3u << 18));   // 2 KB
  float* Lp           = (float*)(ws + (21ull << 20));                 // <=1 MB
  unsigned short* Opb = (unsigned short*)(ws + (22ull << 20));        // KS*4 MB

  k_prep<<<320, 256, 0, stream>>>(input, wq, wo, wqb, wob, Sp);
  k_gn_apply<<<dim3(64, NBATCH), 256, 0, stream>>>(input, Sp, gnw, gnb, xn);
  k_gemm<768, 0><<<dim3(12, 64, NBATCH), 256, 0, stream>>>(wqb, xn, Qf, Kf, Vf, nullptr, nullptr, nullptr);
  if (ws_size >= (54ull << 20)) {
    k_attn<8><<<dim3(16, NHEAD * NBATCH, 8), 256, 0, stream>>>(Qf, Kf, Vf, Opb, Lp);
    k_combine<8><<<512, 256, 0, stream>>>(Opb, Lp, ao);
  } else {
    k_attn<4><<<dim3(16, NHEAD * NBATCH, 4), 256, 0, stream>>>(Qf, Kf, Vf, Opb, Lp);
    k_combine<4><<<512, 256, 0, stream>>>(Opb, Lp, ao);
  }
  k_gemm<256, 1><<<dim3(4, 64, NBATCH), 256, 0, stream>>>(wob, ao, nullptr, nullptr, nullptr, out, ob, input);
}

// Round 5
// 164.307 us; speedup vs baseline: 1.3602x; 1.3602x over previous
//
#include <hip/hip_runtime.h>

// ---- types ----
typedef __bf16        bf16x8 __attribute__((ext_vector_type(8)));
typedef float         f32x4  __attribute__((ext_vector_type(4)));
typedef unsigned short u16x4 __attribute__((ext_vector_type(4)));
typedef unsigned short u16x8 __attribute__((ext_vector_type(8)));
typedef unsigned int  u32x4  __attribute__((ext_vector_type(4)));

#define MFMA16(a,b,c) __builtin_amdgcn_mfma_f32_16x16x32_bf16((a),(b),(c),0,0,0)

static __device__ __forceinline__ unsigned short f2bf(float f) {
  unsigned int u = __builtin_bit_cast(unsigned int, f);
  u += 0x7fffu + ((u >> 16) & 1u);          // RNE; inputs are finite
  return (unsigned short)(u >> 16);
}
// pack 2 floats -> bf16x2 dword, round-half-up via +0x8000 then byte-perm
static __device__ __forceinline__ unsigned int pk2(float a, float b) {
  unsigned int ua = __builtin_bit_cast(unsigned int, a) + 0x8000u;
  unsigned int ub = __builtin_bit_cast(unsigned int, b) + 0x8000u;
  return __builtin_amdgcn_perm(ub, ua, 0x07060302u);
}
static __device__ __forceinline__ unsigned int pk2rne(float a, float b) {
  return (unsigned int)f2bf(a) | ((unsigned int)f2bf(b) << 16);
}
static __device__ __forceinline__ bf16x8 as_bf(u32x4 v) {
  return __builtin_bit_cast(bf16x8, v);
}
static __device__ __forceinline__ float bf2f(unsigned short u) {
  return __builtin_bit_cast(float, ((unsigned int)u) << 16);
}
// async 16B-per-lane global->LDS DMA; LDS image = base + lane*16
static __device__ __forceinline__ void dma16(const unsigned short* g, unsigned short* l) {
  __builtin_amdgcn_global_load_lds((const __attribute__((address_space(1))) unsigned int*)g,
                                   (__attribute__((address_space(3))) unsigned int*)l, 16, 0, 0);
}

// Problem constants
#define SDIM 4096
#define CDIM 256
#define NHEAD 4
#define HDIM 64
#define NBATCH 2

// ---------------------------------------------------------------------------
// 1) merged prep: blocks 0..255 = GN partial stats, 256..319 = weight cast
__global__ __launch_bounds__(256) void k_prep(const float* __restrict__ x,
                                              const float* __restrict__ wq,
                                              const float* __restrict__ wo,
                                              unsigned short* __restrict__ wqb,
                                              unsigned short* __restrict__ wob,
                                              float2* __restrict__ Sp) {
  int j = blockIdx.x, i = threadIdx.x;
  if (j < 256) {
    const float* p = x + (size_t)(j >> 3) * 65536 + (size_t)(j & 7) * 8192;
    float s = 0.f, sq = 0.f;
#pragma unroll
    for (int r = 0; r < 8; ++r) {
      float4 v = *(const float4*)(p + (r * 256 + i) * 4);
      s  += v.x + v.y + v.z + v.w;
      sq += v.x * v.x + v.y * v.y + v.z * v.z + v.w * v.w;
    }
    __shared__ float rs[256], rq[256];
    rs[i] = s; rq[i] = sq;
    __syncthreads();
    for (int off = 128; off > 0; off >>= 1) {
      if (i < off) { rs[i] += rs[i + off]; rq[i] += rq[i + off]; }
      __syncthreads();
    }
    if (i == 0) Sp[j] = make_float2(rs[0], rq[0]);
  } else {
    int t = (j - 256) * 256 + i;
    int e = t * 16;
#pragma unroll
    for (int c = 0; c < 4; ++c) {
      int idx = e + c * 4;
      const float* src = (idx < 768 * 256) ? (wq + idx) : (wo + idx - 768 * 256);
      unsigned short* dst = (idx < 768 * 256) ? (wqb + idx) : (wob + idx - 768 * 256);
      float4 v = *(const float4*)src;
      u16x4 r; r[0] = f2bf(v.x); r[1] = f2bf(v.y); r[2] = f2bf(v.z); r[3] = f2bf(v.w);
      *(u16x4*)dst = r;
    }
  }
}

// ---------------------------------------------------------------------------
// 2) GN apply + transpose: x[b][c][s] fp32 -> xn[b][s][c] bf16 (stats from Sp)
__global__ __launch_bounds__(256) void k_gn_apply(const float* __restrict__ x,
                                                  const float2* __restrict__ Sp,
                                                  const float* __restrict__ gnw,
                                                  const float* __restrict__ gnb,
                                                  unsigned short* __restrict__ xn) {
  __shared__ __attribute__((aligned(16))) unsigned short sT[64 * 268];
  __shared__ float2 sStat[16];
  int b = blockIdx.y, s0 = blockIdx.x * 64;
  int i = threadIdx.x, lane = i & 63, w = i >> 6;
  if (i < 16) {
    float s = 0.f, sq = 0.f;
#pragma unroll
    for (int u = 0; u < 8; ++u) {
      float2 v = Sp[(b * 16 + i) * 8 + u];
      s += v.x; sq += v.y;
    }
    float mean = s * (1.f / 65536.f);
    float var  = sq * (1.f / 65536.f) - mean * mean;
    sStat[i] = make_float2(mean, rsqrtf(var + 1e-5f));
  }
  __syncthreads();
#pragma unroll 4
  for (int r = 0; r < 64; ++r) {
    int c = r * 4 + w;
    float v = x[((size_t)(b * CDIM + c)) * SDIM + s0 + lane];
    float2 st = sStat[c >> 4];
    float nv = (v - st.x) * st.y * gnw[c] + gnb[c];
    sT[lane * 268 + c] = f2bf(nv);
  }
  __syncthreads();
#pragma unroll
  for (int r = 0; r < 16; ++r) {
    int sl = r * 4 + w;
    u16x4 v = *(const u16x4*)&sT[sl * 268 + lane * 4];
    *(u16x4*)&xn[((size_t)(b * SDIM + s0 + sl)) * CDIM + lane * 4] = v;
  }
}

// ---------------------------------------------------------------------------
// 3/5) GEMM: D[o][s] = sum_c W[o][c] * X[b][s][c]  (K=256)
//  MODE 0 (QKV): epilogue repacks into MFMA frag-linear layouts:
//    Qf/Kf[bh][tile16 = s/16][ks = d/32][lane][8]  (Q pre-scaled by log2(e)/16)
//    Vf[bh][kt32 = s/32][dt = d/16][lane][8]
//  MODE 1 (proj): fp32 + bias + residual -> outf[b][o][s]
template <int M, int MODE>
__global__ __launch_bounds__(256) void k_gemm(const unsigned short* __restrict__ W,
                                              const unsigned short* __restrict__ X,
                                              unsigned short* __restrict__ Qf,
                                              unsigned short* __restrict__ Kf,
                                              unsigned short* __restrict__ Vf,
                                              float* __restrict__ outf,
                                              const float* __restrict__ bias,
                                              const float* __restrict__ resid) {
  __shared__ __attribute__((aligned(16))) unsigned short sX[64 * 40];
  __shared__ __attribute__((aligned(16))) unsigned short sB[64 * 68];  // bounce [s][o]
  int b = blockIdx.z, s0 = blockIdx.y * 64, o0 = blockIdx.x * 64;
  int i = threadIdx.x, lane = i & 63, w = i >> 6;
  int quad = lane >> 4, m = lane & 15;
  const unsigned short* Xb = X + ((size_t)b * SDIM + s0) * CDIM;
  int ss = i >> 2, cq = i & 3;

  f32x4 acc[4] = {};
#pragma unroll
  for (int k0 = 0; k0 < 256; k0 += 32) {
    u32x4 xv = *(const u32x4*)(Xb + ss * CDIM + k0 + cq * 8);
    *(u32x4*)&sX[ss * 40 + cq * 8] = xv;
    __syncthreads();
    bf16x8 a = as_bf(*(const u32x4*)(W + (o0 + w * 16 + m) * 256 + k0 + quad * 8));
#pragma unroll
    for (int st = 0; st < 4; ++st) {
      bf16x8 bx = as_bf(*(const u32x4*)&sX[(st * 16 + m) * 40 + quad * 8]);
      acc[st] = MFMA16(a, bx, acc[st]);
    }
    __syncthreads();
  }
  if (MODE == 1) {
#pragma unroll
    for (int st = 0; st < 4; ++st)
#pragma unroll
      for (int r = 0; r < 4; ++r) {
        int o = o0 + w * 16 + quad * 4 + r;
        int s = s0 + st * 16 + m;
        size_t idx = ((size_t)b * M + o) * SDIM + s;
        outf[idx] = acc[st][r] + bias[o] + resid[idx];
      }
  } else {
    int sec = (o0 >> 6) % 3;             // 0=Q, 1=K, 2=V
    int h   = o0 / 192;
    int bh  = b * NHEAD + h;
    float qs = (sec == 0) ? 0.09016844f : 1.0f;   // log2(e)/16 folded into Q
#pragma unroll
    for (int st = 0; st < 4; ++st) {
      uint2 pk = make_uint2(pk2rne(acc[st][0] * qs, acc[st][1] * qs),
                            pk2rne(acc[st][2] * qs, acc[st][3] * qs));
      *(uint2*)&sB[(st * 16 + m) * 68 + w * 16 + quad * 4] = pk;
    }
    __syncthreads();
    int lp = i & 63, qp = lp >> 4, mp = lp & 15, t = i >> 6;
    if (sec < 2) {
      unsigned short* base = (sec == 0) ? Qf : Kf;
#pragma unroll
      for (int ks = 0; ks < 2; ++ks) {
        const unsigned short* src = &sB[(t * 16 + mp) * 68 + ks * 32 + qp * 8];
        u16x4 lo = *(const u16x4*)src;
        u16x4 hi = *(const u16x4*)(src + 4);
        unsigned short* dst = base + ((((size_t)bh * 256 + (s0 >> 4) + t) * 2 + ks) * 64 + lp) * 8;
        *(u16x4*)dst = lo;
        *(u16x4*)(dst + 4) = hi;
      }
    } else {
      int kt32l = t >> 1, dts = (t & 1) * 2;
#pragma unroll
      for (int dd = 0; dd < 2; ++dd) {
        int dt = dts + dd;
        u16x8 v;
#pragma unroll
        for (int jj = 0; jj < 8; ++jj)
          v[jj] = sB[(kt32l * 32 + qp * 8 + jj) * 68 + dt * 16 + mp];
        unsigned short* dst = Vf + ((((size_t)bh * 128 + (s0 >> 5) + kt32l) * 4 + dt) * 64 + lp) * 8;
        *(u16x8*)dst = v;
      }
    }
  }
}

// ---------------------------------------------------------------------------
// 4) Flash attention, frag-linear inputs, shared LDS tiles, key-split blocks.
//    Block = (256-q tile, bh, ksplit), 4 waves share staged 32-key K/V tiles
//    (double-buffered global_load_lds, 1 barrier/iter). Fixed-max softmax.
//    Partials: Opb bf16 [ks][bh][q][64], Lp fp32 [ks][bh][q].
//    KS=8 -> grid 1024 blocks = 4 blocks/CU.
//    lb(256,2): VGPR=104 (measured R3) -> 4 waves/SIMD HW-allowed, NO spills.
//    (R4's lb(256,4) forced VGPR=64 and spilled accumulators: FETCH 35->332MB.)
template <int KS>
__global__ __launch_bounds__(256, 2) void k_attn(const unsigned short* __restrict__ Qf,
                                                 const unsigned short* __restrict__ Kf,
                                                 const unsigned short* __restrict__ Vf,
                                                 unsigned short* __restrict__ Opb,
                                                 float* __restrict__ Lp) {
  __shared__ __attribute__((aligned(16))) unsigned short sK[2][2048];
  __shared__ __attribute__((aligned(16))) unsigned short sV[2][2048];
  __shared__ __attribute__((aligned(16))) unsigned short sP[4][64 * 40];
  int bh = blockIdx.y, kk = blockIdx.z;
  int i = threadIdx.x, lane = i & 63, w = i >> 6;
  int quad = lane >> 4, m = lane & 15;
  int qbase = blockIdx.x * 256 + w * 64;
  constexpr int ITERS = SDIM / KS / 32;

  bf16x8 bq[4][2];
#pragma unroll
  for (int qt = 0; qt < 4; ++qt)
#pragma unroll
    for (int ks = 0; ks < 2; ++ks)
      bq[qt][ks] = as_bf(*(const u32x4*)(Qf +
        ((((size_t)bh * 256 + ((qbase >> 4) + qt)) * 2 + ks) * 64 + lane) * 8));

  f32x4 oacc[4][4] = {};
  float li[4] = {0.f, 0.f, 0.f, 0.f};

  auto dma = [&](int it, int buf) {
    int kb16 = kk * (ITERS * 2) + it * 2 + (w >> 1);
    dma16(Kf + ((((size_t)bh * 256 + kb16) * 2 + (w & 1)) * 64 + lane) * 8,
          &sK[buf][w * 512]);
    int kb32 = kk * ITERS + it;
    dma16(Vf + ((((size_t)bh * 128 + kb32) * 4 + w) * 64 + lane) * 8,
          &sV[buf][w * 512]);
  };
  dma(0, 0);

  for (int it = 0; it < ITERS; ++it) {
    int buf = it & 1;
    __syncthreads();
    if (it < ITERS - 1) dma(it + 1, buf ^ 1);

    bf16x8 ak[2][2], av[4];
#pragma unroll
    for (int ky = 0; ky < 2; ++ky)
#pragma unroll
      for (int ks = 0; ks < 2; ++ks)
        ak[ky][ks] = *(const bf16x8*)&sK[buf][((ky * 2 + ks) * 64 + lane) * 8];
#pragma unroll
    for (int dt = 0; dt < 4; ++dt)
      av[dt] = *(const bf16x8*)&sV[buf][(dt * 64 + lane) * 8];

#pragma unroll
    for (int qt = 0; qt < 4; ++qt) {
      f32x4 sc0 = {-18.f, -18.f, -18.f, -18.f};
      f32x4 sc1 = sc0;
      sc0 = MFMA16(ak[0][0], bq[qt][0], sc0);
      sc0 = MFMA16(ak[0][1], bq[qt][1], sc0);
      sc1 = MFMA16(ak[1][0], bq[qt][0], sc1);
      sc1 = MFMA16(ak[1][1], bq[qt][1], sc1);
      float p[8];
#pragma unroll
      for (int r = 0; r < 4; ++r) {
        p[r]     = __builtin_amdgcn_exp2f(sc0[r]);
        p[4 + r] = __builtin_amdgcn_exp2f(sc1[r]);
      }
      li[qt] += ((p[0] + p[1]) + (p[2] + p[3])) + ((p[4] + p[5]) + (p[6] + p[7]));
      int row = (qt * 16 + m) * 40;
      *(uint2*)&sP[w][row + quad * 4]      = make_uint2(pk2(p[0], p[1]), pk2(p[2], p[3]));
      *(uint2*)&sP[w][row + 16 + quad * 4] = make_uint2(pk2(p[4], p[5]), pk2(p[6], p[7]));
    }
#pragma unroll
    for (int qt = 0; qt < 4; ++qt) {
      bf16x8 bp = *(const bf16x8*)&sP[w][(qt * 16 + m) * 40 + quad * 8];
#pragma unroll
      for (int dt = 0; dt < 4; ++dt)
        oacc[qt][dt] = MFMA16(av[dt], bp, oacc[qt][dt]);
    }
  }

  size_t qg = (size_t)(kk * 8 + bh) * SDIM + qbase;
#pragma unroll
  for (int qt = 0; qt < 4; ++qt) {
    li[qt] += __shfl_xor(li[qt], 16);
    li[qt] += __shfl_xor(li[qt], 32);
  }
  if (quad == 0) {
#pragma unroll
    for (int qt = 0; qt < 4; ++qt) Lp[qg + qt * 16 + m] = li[qt];
  }
#pragma unroll
  for (int qt = 0; qt < 4; ++qt)
#pragma unroll
    for (int dt = 0; dt < 4; ++dt) {
      uint2 pk = make_uint2(pk2rne(oacc[qt][dt][0], oacc[qt][dt][1]),
                            pk2rne(oacc[qt][dt][2], oacc[qt][dt][3]));
      *(uint2*)&Opb[(qg + qt * 16 + m) * 64 + dt * 16 + quad * 4] = pk;
    }
}

// ---------------------------------------------------------------------------
// 5) combine partials: ao[b][q][h*64+d] = sum_ks Opb / sum_ks Lp  (bf16)
template <int KS>
__global__ __launch_bounds__(256) void k_combine(const unsigned short* __restrict__ Opb,
                                                 const float* __restrict__ Lp,
                                                 unsigned short* __restrict__ ao) {
  int gid = blockIdx.x * 256 + threadIdx.x;
  int bh = gid >> 14, rem = gid & 16383, q = rem >> 2, dq = rem & 3;
  float li = 0.f, o[16];
#pragma unroll
  for (int e = 0; e < 16; ++e) o[e] = 0.f;
#pragma unroll
  for (int ks = 0; ks < KS; ++ks) {
    size_t base = (size_t)(ks * 8 + bh) * SDIM + q;
    li += Lp[base];
    const unsigned short* p = Opb + base * 64 + dq * 16;
    u16x8 a = *(const u16x8*)p, b2 = *(const u16x8*)(p + 8);
#pragma unroll
    for (int e = 0; e < 8; ++e) { o[e] += bf2f(a[e]); o[8 + e] += bf2f(b2[e]); }
  }
  float inv = 1.f / li;
  unsigned int dw[8];
#pragma unroll
  for (int e = 0; e < 8; ++e) dw[e] = pk2rne(o[2 * e] * inv, o[2 * e + 1] * inv);
  unsigned short* dst = ao + ((size_t)((bh >> 2) * SDIM + q)) * CDIM + (bh & 3) * HDIM + dq * 16;
  *(u32x4*)dst       = u32x4{dw[0], dw[1], dw[2], dw[3]};
  *(u32x4*)(dst + 8) = u32x4{dw[4], dw[5], dw[6], dw[7]};
}

// ---------------------------------------------------------------------------
extern "C" void kernel_launch(void* const* d_in, const int* in_sizes, int n_in,
                              void* d_out, int out_size, void* d_ws, size_t ws_size,
                              hipStream_t stream) {
  const float* input = (const float*)d_in[0];
  const float* gnw   = (const float*)d_in[1];
  const float* gnb   = (const float*)d_in[2];
  const float* wq    = (const float*)d_in[3];
  const float* wo    = (const float*)d_in[4];
  const float* ob    = (const float*)d_in[5];
  float* out = (float*)d_out;

  char* ws = (char*)d_ws;
  unsigned short* xn  = (unsigned short*)(ws);                        // 4 MB [b][s][c]
  unsigned short* Qf  = (unsigned short*)(ws + (4ull  << 20));        // 4 MB frag-linear
  unsigned short* Kf  = (unsigned short*)(ws + (8ull  << 20));        // 4 MB
  unsigned short* Vf  = (unsigned short*)(ws + (12ull << 20));        // 4 MB
  unsigned short* ao  = (unsigned short*)(ws + (16ull << 20));        // 4 MB [b][s][c]
  unsigned short* wqb = (unsigned short*)(ws + (20ull << 20));        // 384 KB
  unsigned short* wob = (unsigned short*)(ws + (20ull << 20) + (1u << 19)); // 128 KB
  float2* Sp          = (float2*)(ws + (20ull << 20) + (3u << 18));   // 2 KB
  float* Lp           = (float*)(ws + (21ull << 20));                 // <=1 MB
  unsigned short* Opb = (unsigned short*)(ws + (22ull << 20));        // KS*4 MB

  k_prep<<<320, 256, 0, stream>>>(input, wq, wo, wqb, wob, Sp);
  k_gn_apply<<<dim3(64, NBATCH), 256, 0, stream>>>(input, Sp, gnw, gnb, xn);
  k_gemm<768, 0><<<dim3(12, 64, NBATCH), 256, 0, stream>>>(wqb, xn, Qf, Kf, Vf, nullptr, nullptr, nullptr);
  if (ws_size >= (54ull << 20)) {
    k_attn<8><<<dim3(16, NHEAD * NBATCH, 8), 256, 0, stream>>>(Qf, Kf, Vf, Opb, Lp);
    k_combine<8><<<512, 256, 0, stream>>>(Opb, Lp, ao);
  } else {
    k_attn<4><<<dim3(16, NHEAD * NBATCH, 4), 256, 0, stream>>>(Qf, Kf, Vf, Opb, Lp);
    k_combine<4><<<512, 256, 0, stream>>>(Opb, Lp, ao);
  }
  k_gemm<256, 1><<<dim3(4, 64, NBATCH), 256, 0, stream>>>(wob, ao, nullptr, nullptr, nullptr, out, ob, input);
}

// Round 6
// 147.043 us; speedup vs baseline: 1.5199x; 1.1174x over previous
//
#include <hip/hip_runtime.h>

// ---- types ----
typedef __bf16        bf16x8 __attribute__((ext_vector_type(8)));
typedef float         f32x4  __attribute__((ext_vector_type(4)));
typedef unsigned short u16x4 __attribute__((ext_vector_type(4)));
typedef unsigned short u16x8 __attribute__((ext_vector_type(8)));
typedef unsigned int  u32x4  __attribute__((ext_vector_type(4)));

#define MFMA16(a,b,c) __builtin_amdgcn_mfma_f32_16x16x32_bf16((a),(b),(c),0,0,0)

static __device__ __forceinline__ unsigned short f2bf(float f) {
  unsigned int u = __builtin_bit_cast(unsigned int, f);
  u += 0x7fffu + ((u >> 16) & 1u);          // RNE; inputs are finite
  return (unsigned short)(u >> 16);
}
// pack 2 floats -> bf16x2 dword, round-half-up via +0x8000 then byte-perm
static __device__ __forceinline__ unsigned int pk2(float a, float b) {
  unsigned int ua = __builtin_bit_cast(unsigned int, a) + 0x8000u;
  unsigned int ub = __builtin_bit_cast(unsigned int, b) + 0x8000u;
  return __builtin_amdgcn_perm(ub, ua, 0x07060302u);
}
static __device__ __forceinline__ unsigned int pk2rne(float a, float b) {
  return (unsigned int)f2bf(a) | ((unsigned int)f2bf(b) << 16);
}
static __device__ __forceinline__ bf16x8 as_bf(u32x4 v) {
  return __builtin_bit_cast(bf16x8, v);
}
static __device__ __forceinline__ float bf2f(unsigned short u) {
  return __builtin_bit_cast(float, ((unsigned int)u) << 16);
}
// async 16B-per-lane global->LDS DMA; LDS image = base + lane*16
static __device__ __forceinline__ void dma16(const unsigned short* g, unsigned short* l) {
  __builtin_amdgcn_global_load_lds((const __attribute__((address_space(1))) unsigned int*)g,
                                   (__attribute__((address_space(3))) unsigned int*)l, 16, 0, 0);
}

// Problem constants
#define SDIM 4096
#define CDIM 256
#define NHEAD 4
#define HDIM 64
#define NBATCH 2
#define KSPLIT 4

// ---------------------------------------------------------------------------
// 1) merged prep: blocks 0..255 = GN partial stats, 256..319 = weight cast
__global__ __launch_bounds__(256) void k_prep(const float* __restrict__ x,
                                              const float* __restrict__ wq,
                                              const float* __restrict__ wo,
                                              unsigned short* __restrict__ wqb,
                                              unsigned short* __restrict__ wob,
                                              float2* __restrict__ Sp) {
  int j = blockIdx.x, i = threadIdx.x;
  if (j < 256) {
    const float* p = x + (size_t)(j >> 3) * 65536 + (size_t)(j & 7) * 8192;
    float s = 0.f, sq = 0.f;
#pragma unroll
    for (int r = 0; r < 8; ++r) {
      float4 v = *(const float4*)(p + (r * 256 + i) * 4);
      s  += v.x + v.y + v.z + v.w;
      sq += v.x * v.x + v.y * v.y + v.z * v.z + v.w * v.w;
    }
    __shared__ float rs[256], rq[256];
    rs[i] = s; rq[i] = sq;
    __syncthreads();
    for (int off = 128; off > 0; off >>= 1) {
      if (i < off) { rs[i] += rs[i + off]; rq[i] += rq[i + off]; }
      __syncthreads();
    }
    if (i == 0) Sp[j] = make_float2(rs[0], rq[0]);
  } else {
    int t = (j - 256) * 256 + i;
    int e = t * 16;
#pragma unroll
    for (int c = 0; c < 4; ++c) {
      int idx = e + c * 4;
      const float* src = (idx < 768 * 256) ? (wq + idx) : (wo + idx - 768 * 256);
      unsigned short* dst = (idx < 768 * 256) ? (wqb + idx) : (wob + idx - 768 * 256);
      float4 v = *(const float4*)src;
      u16x4 r; r[0] = f2bf(v.x); r[1] = f2bf(v.y); r[2] = f2bf(v.z); r[3] = f2bf(v.w);
      *(u16x4*)dst = r;
    }
  }
}

// ---------------------------------------------------------------------------
// 2) GN apply + transpose: x[b][c][s] fp32 -> xn[b][s][c] bf16 (stats from Sp)
__global__ __launch_bounds__(256) void k_gn_apply(const float* __restrict__ x,
                                                  const float2* __restrict__ Sp,
                                                  const float* __restrict__ gnw,
                                                  const float* __restrict__ gnb,
                                                  unsigned short* __restrict__ xn) {
  __shared__ __attribute__((aligned(16))) unsigned short sT[64 * 268];
  __shared__ float2 sStat[16];
  int b = blockIdx.y, s0 = blockIdx.x * 64;
  int i = threadIdx.x, lane = i & 63, w = i >> 6;
  if (i < 16) {
    float s = 0.f, sq = 0.f;
#pragma unroll
    for (int u = 0; u < 8; ++u) {
      float2 v = Sp[(b * 16 + i) * 8 + u];
      s += v.x; sq += v.y;
    }
    float mean = s * (1.f / 65536.f);
    float var  = sq * (1.f / 65536.f) - mean * mean;
    sStat[i] = make_float2(mean, rsqrtf(var + 1e-5f));
  }
  __syncthreads();
#pragma unroll 4
  for (int r = 0; r < 64; ++r) {
    int c = r * 4 + w;
    float v = x[((size_t)(b * CDIM + c)) * SDIM + s0 + lane];
    float2 st = sStat[c >> 4];
    float nv = (v - st.x) * st.y * gnw[c] + gnb[c];
    sT[lane * 268 + c] = f2bf(nv);
  }
  __syncthreads();
#pragma unroll
  for (int r = 0; r < 16; ++r) {
    int sl = r * 4 + w;
    u16x4 v = *(const u16x4*)&sT[sl * 268 + lane * 4];
    *(u16x4*)&xn[((size_t)(b * SDIM + s0 + sl)) * CDIM + lane * 4] = v;
  }
}

// ---------------------------------------------------------------------------
// 3/5) GEMM: D[o][s] = sum_c W[o][c] * X[b][s][c]  (K=256)
//  MODE 0 (QKV): epilogue repacks into MFMA frag-linear layouts:
//    Qf/Kf[bh][tile16 = s/16][ks = d/32][lane][8]  (Q pre-scaled by log2(e)/16)
//    Vf[bh][kt32 = s/32][dt = d/16][lane][8]
//  MODE 1 (proj): fp32 + bias + residual -> outf[b][o][s]
template <int M, int MODE>
__global__ __launch_bounds__(256) void k_gemm(const unsigned short* __restrict__ W,
                                              const unsigned short* __restrict__ X,
                                              unsigned short* __restrict__ Qf,
                                              unsigned short* __restrict__ Kf,
                                              unsigned short* __restrict__ Vf,
                                              float* __restrict__ outf,
                                              const float* __restrict__ bias,
                                              const float* __restrict__ resid) {
  __shared__ __attribute__((aligned(16))) unsigned short sX[64 * 40];
  __shared__ __attribute__((aligned(16))) unsigned short sB[64 * 68];  // bounce [s][o]
  int b = blockIdx.z, s0 = blockIdx.y * 64, o0 = blockIdx.x * 64;
  int i = threadIdx.x, lane = i & 63, w = i >> 6;
  int quad = lane >> 4, m = lane & 15;
  const unsigned short* Xb = X + ((size_t)b * SDIM + s0) * CDIM;
  int ss = i >> 2, cq = i & 3;

  f32x4 acc[4] = {};
#pragma unroll
  for (int k0 = 0; k0 < 256; k0 += 32) {
    u32x4 xv = *(const u32x4*)(Xb + ss * CDIM + k0 + cq * 8);
    *(u32x4*)&sX[ss * 40 + cq * 8] = xv;
    __syncthreads();
    bf16x8 a = as_bf(*(const u32x4*)(W + (o0 + w * 16 + m) * 256 + k0 + quad * 8));
#pragma unroll
    for (int st = 0; st < 4; ++st) {
      bf16x8 bx = as_bf(*(const u32x4*)&sX[(st * 16 + m) * 40 + quad * 8]);
      acc[st] = MFMA16(a, bx, acc[st]);
    }
    __syncthreads();
  }
  if (MODE == 1) {
#pragma unroll
    for (int st = 0; st < 4; ++st)
#pragma unroll
      for (int r = 0; r < 4; ++r) {
        int o = o0 + w * 16 + quad * 4 + r;
        int s = s0 + st * 16 + m;
        size_t idx = ((size_t)b * M + o) * SDIM + s;
        outf[idx] = acc[st][r] + bias[o] + resid[idx];
      }
  } else {
    int sec = (o0 >> 6) % 3;             // 0=Q, 1=K, 2=V
    int h   = o0 / 192;
    int bh  = b * NHEAD + h;
    float qs = (sec == 0) ? 0.09016844f : 1.0f;   // log2(e)/16 folded into Q
#pragma unroll
    for (int st = 0; st < 4; ++st) {
      uint2 pk = make_uint2(pk2rne(acc[st][0] * qs, acc[st][1] * qs),
                            pk2rne(acc[st][2] * qs, acc[st][3] * qs));
      *(uint2*)&sB[(st * 16 + m) * 68 + w * 16 + quad * 4] = pk;
    }
    __syncthreads();
    int lp = i & 63, qp = lp >> 4, mp = lp & 15, t = i >> 6;
    if (sec < 2) {
      unsigned short* base = (sec == 0) ? Qf : Kf;
#pragma unroll
      for (int ks = 0; ks < 2; ++ks) {
        const unsigned short* src = &sB[(t * 16 + mp) * 68 + ks * 32 + qp * 8];
        u16x4 lo = *(const u16x4*)src;
        u16x4 hi = *(const u16x4*)(src + 4);
        unsigned short* dst = base + ((((size_t)bh * 256 + (s0 >> 4) + t) * 2 + ks) * 64 + lp) * 8;
        *(u16x4*)dst = lo;
        *(u16x4*)(dst + 4) = hi;
      }
    } else {
      int kt32l = t >> 1, dts = (t & 1) * 2;
#pragma unroll
      for (int dd = 0; dd < 2; ++dd) {
        int dt = dts + dd;
        u16x8 v;
#pragma unroll
        for (int jj = 0; jj < 8; ++jj)
          v[jj] = sB[(kt32l * 32 + qp * 8 + jj) * 68 + dt * 16 + mp];
        unsigned short* dst = Vf + ((((size_t)bh * 128 + (s0 >> 5) + kt32l) * 4 + dt) * 64 + lp) * 8;
        *(u16x8*)dst = v;
      }
    }
  }
}

// ---------------------------------------------------------------------------
// 4) Flash attention v3: 32q per wave (128q block), waves share staged K/V
//    tiles and each covers the FULL key range of its split -> no cross-wave
//    combine. oacc = 32 AGPR, arch VGPR ~90 -> total <=128 => 4 waves/SIMD
//    with lb(256,4). (R4 lesson: only safe because working set now fits.)
//    Partials: Opb bf16 [ks][bh][q][64], Lp fp32 [ks][bh][q].
__global__ __launch_bounds__(256, 4) void k_attn(const unsigned short* __restrict__ Qf,
                                                 const unsigned short* __restrict__ Kf,
                                                 const unsigned short* __restrict__ Vf,
                                                 unsigned short* __restrict__ Opb,
                                                 float* __restrict__ Lp) {
  __shared__ __attribute__((aligned(16))) unsigned short sK[2][2048];  // 4 slots x 64 lanes x 8
  __shared__ __attribute__((aligned(16))) unsigned short sV[2][2048];
  __shared__ __attribute__((aligned(16))) unsigned short sP[4][32 * 40]; // per-wave [32q][32k pad40]
  int bh = blockIdx.y, kk = blockIdx.z;
  int i = threadIdx.x, lane = i & 63, w = i >> 6;
  int quad = lane >> 4, m = lane & 15;
  constexpr int ITERS = SDIM / KSPLIT / 32;

  // Q B-frags: wave w owns q-tiles {blockIdx.x*8 + w*2, +1}
  bf16x8 bq[2][2];
#pragma unroll
  for (int qt = 0; qt < 2; ++qt)
#pragma unroll
    for (int ks = 0; ks < 2; ++ks)
      bq[qt][ks] = as_bf(*(const u32x4*)(Qf +
        ((((size_t)bh * 256 + (blockIdx.x * 8 + w * 2 + qt)) * 2 + ks) * 64 + lane) * 8));

  f32x4 oacc[2][4] = {};
  float li[2] = {0.f, 0.f};

  // per-iter DMA: wave w stages K slot w (ky=w>>1, ks=w&1) and V slot w (dt=w)
  auto dma = [&](int it, int buf) {
    int kb16 = kk * (ITERS * 2) + it * 2 + (w >> 1);
    dma16(Kf + ((((size_t)bh * 256 + kb16) * 2 + (w & 1)) * 64 + lane) * 8,
          &sK[buf][w * 512]);
    int kb32 = kk * ITERS + it;
    dma16(Vf + ((((size_t)bh * 128 + kb32) * 4 + w) * 64 + lane) * 8,
          &sV[buf][w * 512]);
  };
  dma(0, 0);

  for (int it = 0; it < ITERS; ++it) {
    int buf = it & 1;
    __syncthreads();                      // drains DMA (vmcnt) then barrier
    if (it < ITERS - 1) dma(it + 1, buf ^ 1);

    // ---- QK^T + softmax + pack (ak live) ----
    {
      bf16x8 ak[2][2];
#pragma unroll
      for (int ky = 0; ky < 2; ++ky)
#pragma unroll
        for (int ks = 0; ks < 2; ++ks)
          ak[ky][ks] = *(const bf16x8*)&sK[buf][((ky * 2 + ks) * 64 + lane) * 8];
#pragma unroll
      for (int qt = 0; qt < 2; ++qt) {
        f32x4 sc0 = {-18.f, -18.f, -18.f, -18.f};   // fixed-max shift in C-init
        f32x4 sc1 = sc0;
        sc0 = MFMA16(ak[0][0], bq[qt][0], sc0);
        sc0 = MFMA16(ak[0][1], bq[qt][1], sc0);
        sc1 = MFMA16(ak[1][0], bq[qt][0], sc1);
        sc1 = MFMA16(ak[1][1], bq[qt][1], sc1);
        float p[8];
#pragma unroll
        for (int r = 0; r < 4; ++r) {
          p[r]     = __builtin_amdgcn_exp2f(sc0[r]);
          p[4 + r] = __builtin_amdgcn_exp2f(sc1[r]);
        }
        li[qt] += ((p[0] + p[1]) + (p[2] + p[3])) + ((p[4] + p[5]) + (p[6] + p[7]));
        int row = (qt * 16 + m) * 40;
        *(uint2*)&sP[w][row + quad * 4]      = make_uint2(pk2(p[0], p[1]), pk2(p[2], p[3]));
        *(uint2*)&sP[w][row + 16 + quad * 4] = make_uint2(pk2(p[4], p[5]), pk2(p[6], p[7]));
      }
    }
    // ---- PV (av live; sP is same-wave data, lgkm wait only) ----
    {
      bf16x8 av[4];
#pragma unroll
      for (int dt = 0; dt < 4; ++dt)
        av[dt] = *(const bf16x8*)&sV[buf][(dt * 64 + lane) * 8];
#pragma unroll
      for (int qt = 0; qt < 2; ++qt) {
        bf16x8 bp = *(const bf16x8*)&sP[w][(qt * 16 + m) * 40 + quad * 8];
#pragma unroll
        for (int dt = 0; dt < 4; ++dt)
          oacc[qt][dt] = MFMA16(av[dt], bp, oacc[qt][dt]);
      }
    }
  }

  // epilogue: quads hold disjoint key subsets -> reduce li, store partials
  size_t qg = (size_t)(kk * 8 + bh) * SDIM + blockIdx.x * 128 + w * 32;
#pragma unroll
  for (int qt = 0; qt < 2; ++qt) {
    li[qt] += __shfl_xor(li[qt], 16);
    li[qt] += __shfl_xor(li[qt], 32);
  }
  if (quad == 0) {
#pragma unroll
    for (int qt = 0; qt < 2; ++qt) Lp[qg + qt * 16 + m] = li[qt];
  }
#pragma unroll
  for (int qt = 0; qt < 2; ++qt)
#pragma unroll
    for (int dt = 0; dt < 4; ++dt) {
      uint2 pk = make_uint2(pk2rne(oacc[qt][dt][0], oacc[qt][dt][1]),
                            pk2rne(oacc[qt][dt][2], oacc[qt][dt][3]));
      *(uint2*)&Opb[(qg + qt * 16 + m) * 64 + dt * 16 + quad * 4] = pk;
    }
}

// ---------------------------------------------------------------------------
// 5) combine partials: ao[b][q][h*64+d] = sum_ks Opb / sum_ks Lp  (bf16)
__global__ __launch_bounds__(256) void k_combine(const unsigned short* __restrict__ Opb,
                                                 const float* __restrict__ Lp,
                                                 unsigned short* __restrict__ ao) {
  int gid = blockIdx.x * 256 + threadIdx.x;
  int bh = gid >> 14, rem = gid & 16383, q = rem >> 2, dq = rem & 3;
  float li = 0.f, o[16];
#pragma unroll
  for (int e = 0; e < 16; ++e) o[e] = 0.f;
#pragma unroll
  for (int ks = 0; ks < KSPLIT; ++ks) {
    size_t base = (size_t)(ks * 8 + bh) * SDIM + q;
    li += Lp[base];
    const unsigned short* p = Opb + base * 64 + dq * 16;
    u16x8 a = *(const u16x8*)p, b2 = *(const u16x8*)(p + 8);
#pragma unroll
    for (int e = 0; e < 8; ++e) { o[e] += bf2f(a[e]); o[8 + e] += bf2f(b2[e]); }
  }
  float inv = 1.f / li;
  unsigned int dw[8];
#pragma unroll
  for (int e = 0; e < 8; ++e) dw[e] = pk2rne(o[2 * e] * inv, o[2 * e + 1] * inv);
  unsigned short* dst = ao + ((size_t)((bh >> 2) * SDIM + q)) * CDIM + (bh & 3) * HDIM + dq * 16;
  *(u32x4*)dst       = u32x4{dw[0], dw[1], dw[2], dw[3]};
  *(u32x4*)(dst + 8) = u32x4{dw[4], dw[5], dw[6], dw[7]};
}

// ---------------------------------------------------------------------------
extern "C" void kernel_launch(void* const* d_in, const int* in_sizes, int n_in,
                              void* d_out, int out_size, void* d_ws, size_t ws_size,
                              hipStream_t stream) {
  const float* input = (const float*)d_in[0];
  const float* gnw   = (const float*)d_in[1];
  const float* gnb   = (const float*)d_in[2];
  const float* wq    = (const float*)d_in[3];
  const float* wo    = (const float*)d_in[4];
  const float* ob    = (const float*)d_in[5];
  float* out = (float*)d_out;

  char* ws = (char*)d_ws;
  unsigned short* xn  = (unsigned short*)(ws);                        // 4 MB [b][s][c]
  unsigned short* Qf  = (unsigned short*)(ws + (4ull  << 20));        // 4 MB frag-linear
  unsigned short* Kf  = (unsigned short*)(ws + (8ull  << 20));        // 4 MB
  unsigned short* Vf  = (unsigned short*)(ws + (12ull << 20));        // 4 MB
  unsigned short* ao  = (unsigned short*)(ws + (16ull << 20));        // 4 MB [b][s][c]
  unsigned short* wqb = (unsigned short*)(ws + (20ull << 20));        // 384 KB
  unsigned short* wob = (unsigned short*)(ws + (20ull << 20) + (1u << 19)); // 128 KB
  float2* Sp          = (float2*)(ws + (20ull << 20) + (3u << 18));   // 2 KB
  float* Lp           = (float*)(ws + (21ull << 20));                 // <=1 MB
  unsigned short* Opb = (unsigned short*)(ws + (22ull << 20));        // 16 MB

  k_prep<<<320, 256, 0, stream>>>(input, wq, wo, wqb, wob, Sp);
  k_gn_apply<<<dim3(64, NBATCH), 256, 0, stream>>>(input, Sp, gnw, gnb, xn);
  k_gemm<768, 0><<<dim3(12, 64, NBATCH), 256, 0, stream>>>(wqb, xn, Qf, Kf, Vf, nullptr, nullptr, nullptr);
  k_attn<<<dim3(32, NHEAD * NBATCH, KSPLIT), 256, 0, stream>>>(Qf, Kf, Vf, Opb, Lp);
  k_combine<<<512, 256, 0, stream>>>(Opb, Lp, ao);
  k_gemm<256, 1><<<dim3(4, 64, NBATCH), 256, 0, stream>>>(wob, ao, nullptr, nullptr, nullptr, out, ob, input);
}